// Round 1
// baseline (21916.481 us; speedup 1.0000x reference)
//
#include <hip/hip_runtime.h>
#include <hip/hip_bf16.h>

// ---------------------------------------------------------------------------
// RNNAttentionModel: 3-layer LSTM + causal self-attention + decoder, MI355X.
// All float tensors assumed stored as bf16 on device (detected at runtime via
// a probe kernel writing a flag; every kernel has an f32 fallback load path).
// T=256 B=16 H=2048 L=3 V=32000
// ---------------------------------------------------------------------------

typedef __attribute__((ext_vector_type(8))) short short8;
typedef __attribute__((ext_vector_type(4))) float f32x4;

#define AS1 __attribute__((address_space(1)))
#define AS3 __attribute__((address_space(3)))

__device__ __forceinline__ void g2l16(const void* g, void* l) {
    __builtin_amdgcn_global_load_lds((const AS1 void*)g, (AS3 void*)l, 16, 0, 0);
}

__device__ __forceinline__ float b2f(unsigned short u) {
    union { unsigned int u; float f; } x; x.u = ((unsigned int)u) << 16; return x.f;
}
__device__ __forceinline__ unsigned short f2b(float f) {
    union { float f; unsigned int u; } x; x.f = f;
    unsigned int u = x.u;
    unsigned int r = (u + 0x7FFFu + ((u >> 16) & 1u)) >> 16;
    return (unsigned short)r;
}
__device__ __forceinline__ short8 pack8(float4 a, float4 b) {
    short8 r;
    r[0] = (short)f2b(a.x); r[1] = (short)f2b(a.y);
    r[2] = (short)f2b(a.z); r[3] = (short)f2b(a.w);
    r[4] = (short)f2b(b.x); r[5] = (short)f2b(b.y);
    r[6] = (short)f2b(b.z); r[7] = (short)f2b(b.w);
    return r;
}
__device__ __forceinline__ float sigf(float x) { return 1.f / (1.f + expf(-x)); }

// ---------------------------------------------------------------------------
// dtype probe: if emb_W really holds f32 bits, reading it as bf16 pairs gives
// low-halves with ~uniform exponent fields -> many |x|>=64. Genuine bf16
// embedding weights are all |x| < 1.
// ---------------------------------------------------------------------------
__global__ void detect_dtype(const unsigned short* emb, int* flag) {
    __shared__ int cnt;
    if (threadIdx.x == 0) cnt = 0;
    __syncthreads();
    int local = 0;
    for (int i = threadIdx.x; i < 8192; i += 256) {
        unsigned short u = emb[i];
        int e = (u >> 7) & 0xFF;
        if (e >= 0x85) local++;   // |x| >= 64
    }
    atomicAdd(&cnt, local);
    __syncthreads();
    if (threadIdx.x == 0) *flag = (cnt > 64) ? 1 : 0;  // 1 = inputs are f32
}

// ---------------------------------------------------------------------------
// Embedding gather: X[row,:] = emb_W[ids[row],:]  (row = t*16+b), bf16 out.
// ---------------------------------------------------------------------------
__global__ void embed_kernel(const int* __restrict__ ids, const void* __restrict__ emb,
                             const int* __restrict__ flagp, unsigned short* __restrict__ X) {
    int row = blockIdx.x, tid = threadIdx.x;
    int id = ids[row];
    long src = (long)id * 2048 + tid * 8;
    long dst = (long)row * 2048 + tid * 8;
    if (!*flagp) {
        *(uint4*)&X[dst] = *(const uint4*)((const unsigned short*)emb + src);
    } else {
        const float* e = (const float*)emb + src;
        float4 f0 = *(const float4*)e;
        float4 f1 = *(const float4*)(e + 4);
        *(short8*)&X[dst] = pack8(f0, f1);
    }
}

__global__ void init_state(const void* __restrict__ h0, const void* __restrict__ c0,
                           long off, const int* __restrict__ flagp,
                           unsigned short* __restrict__ h0buf, float* __restrict__ c) {
    long i = (long)blockIdx.x * 256 + threadIdx.x;   // 32768 total
    if (!*flagp) {
        h0buf[i] = ((const unsigned short*)h0)[off + i];
        c[i] = b2f(((const unsigned short*)c0)[off + i]);
    } else {
        h0buf[i] = f2b(((const float*)h0)[off + i]);
        c[i] = ((const float*)c0)[off + i];
    }
}

// ---------------------------------------------------------------------------
// Generic C = alpha*(A @ B^T) + bias, optional tanh. A is always internal
// bf16 (K-contiguous, leading dim lda, batch stride sA). B may be an external
// input (bf16 or f32 per flag). C: mode 0=f32, 1=bf16, 2=external (bf16 unless
// flag says f32). 128x128 tile, BK=32, 256 threads, mfma_f32_16x16x32_bf16.
// Grid: (N/128, M/128, batch).
// ---------------------------------------------------------------------------
__global__ __launch_bounds__(256) void gemm_bt(
        const unsigned short* __restrict__ A,
        const void* __restrict__ Braw, long boff, int b_ext,
        const void* __restrict__ biasraw, long biasoff, int has_bias, int bias_ext,
        void* __restrict__ Cp, int c_mode,
        const int* __restrict__ flagp,
        int M, int N, int K,
        long lda, long ldb, long ldc,
        long sA, long sB, long sC,
        float alpha, int do_tanh) {
    (void)M; (void)N;
    __shared__ __align__(16) unsigned short lds_a[128 * 32];
    __shared__ __align__(16) unsigned short lds_b[128 * 32];

    int tid = threadIdx.x;
    int lane = tid & 63, w = tid >> 6;
    int quad = lane >> 4, m16 = lane & 15;
    int bx = blockIdx.x, by = blockIdx.y, bz = blockIdx.z;
    long row0 = (long)by * 128, col0 = (long)bx * 128;

    int flg = *flagp;
    int bf32 = b_ext && flg;
    int cm = c_mode;
    if (cm == 2) cm = flg ? 0 : 1;

    const unsigned short* Ab = A + (long)bz * sA;
    const unsigned short* B16 = (const unsigned short*)Braw + boff + (long)bz * sB;
    const float* B32 = (const float*)Braw + boff + (long)bz * sB;

    f32x4 acc[4][4];
    for (int i = 0; i < 4; i++)
        for (int j = 0; j < 4; j++)
            acc[i][j] = (f32x4){0.f, 0.f, 0.f, 0.f};

    int rbase = (w >> 1) * 64, cbase = (w & 1) * 64;

    for (int k0 = 0; k0 < K; k0 += 32) {
        __syncthreads();
        // stage A tile (128 rows x 32 k) via async global->LDS, 16B/lane
        for (int i = 0; i < 2; i++) {
            int cch = w * 128 + i * 64 + lane;
            int r = cch >> 2, q = cch & 3;
            const unsigned short* gp = Ab + (row0 + r) * lda + k0 + q * 8;
            g2l16(gp, &lds_a[(w * 128 + i * 64) * 8]);
        }
        if (!bf32) {
            for (int i = 0; i < 2; i++) {
                int cch = w * 128 + i * 64 + lane;
                int r = cch >> 2, q = cch & 3;
                const unsigned short* gp = B16 + (col0 + r) * ldb + k0 + q * 8;
                g2l16(gp, &lds_b[(w * 128 + i * 64) * 8]);
            }
        } else {
            for (int i = 0; i < 2; i++) {
                int cch = w * 128 + i * 64 + lane;
                int r = cch >> 2, q = cch & 3;
                const float* gp = B32 + (col0 + r) * ldb + k0 + q * 8;
                float4 f0 = *(const float4*)gp;
                float4 f1 = *(const float4*)(gp + 4);
                *(short8*)&lds_b[(long)cch * 8] = pack8(f0, f1);
            }
        }
        __syncthreads();

        short8 af[4], bfr[4];
        for (int t = 0; t < 4; t++) {
            af[t]  = *(const short8*)&lds_a[(rbase + t * 16 + m16) * 32 + quad * 8];
            bfr[t] = *(const short8*)&lds_b[(cbase + t * 16 + m16) * 32 + quad * 8];
        }
        for (int i = 0; i < 4; i++)
            for (int j = 0; j < 4; j++)
                acc[i][j] = __builtin_amdgcn_mfma_f32_16x16x32_bf16(af[i], bfr[j], acc[i][j], 0, 0, 0);
    }

    // epilogue: C/D layout col=lane&15, row=quad*4+e
    for (int j = 0; j < 4; j++) {
        long col = col0 + cbase + j * 16 + m16;
        float bv = 0.f;
        if (has_bias) {
            if (bias_ext && flg) bv = ((const float*)biasraw)[biasoff + col];
            else bv = b2f(((const unsigned short*)biasraw)[biasoff + col]);
        }
        for (int i = 0; i < 4; i++) {
            for (int e = 0; e < 4; e++) {
                long row = row0 + rbase + i * 16 + quad * 4 + e;
                float v = acc[i][j][e] * alpha + bv;
                if (do_tanh) v = tanhf(v);
                long idx = row * ldc + (long)bz * sC + col;
                if (cm == 0) ((float*)Cp)[idx] = v;
                else ((unsigned short*)Cp)[idx] = f2b(v);
            }
        }
    }
}

// ---------------------------------------------------------------------------
// One LSTM time step: gates = G[t] + h_{t-1} @ Whh^T, then cell update.
// 128 blocks x 512 threads. Block bk owns 16 hidden units (all 4 gate groups);
// wave w: gate group w&3, K-half w>>2 (K=1024 each). fp32 c state; h out bf16.
// ---------------------------------------------------------------------------
__global__ __launch_bounds__(512) void lstm_step(
        const float* __restrict__ Gt,            // [16, 8192]
        const void* __restrict__ Wraw, long woff,
        const int* __restrict__ flagp,
        const unsigned short* __restrict__ hin,  // [16, 2048] bf16
        unsigned short* __restrict__ hout,       // [16, 2048] bf16
        float* __restrict__ c) {                 // [16, 2048] f32
    __shared__ float lds[8 * 256];
    int tid = threadIdx.x;
    int lane = tid & 63, w = tid >> 6;
    int g = w & 3, kh = w >> 2;
    int bk = blockIdx.x;
    int quad = lane >> 4, m16 = lane & 15;
    int wf32 = *flagp;
    const unsigned short* W16 = (const unsigned short*)Wraw + woff;
    const float* W32 = (const float*)Wraw + woff;
    long wr = (long)(g * 2048 + bk * 16 + m16) * 2048;
    long abase = (long)m16 * 2048;

    f32x4 acc = (f32x4){0.f, 0.f, 0.f, 0.f};
    if (!wf32) {
        #pragma unroll 8
        for (int it = 0; it < 32; it++) {
            int k = kh * 1024 + it * 32 + quad * 8;
            short8 av = *(const short8*)&hin[abase + k];
            short8 bv = *(const short8*)&W16[wr + k];
            acc = __builtin_amdgcn_mfma_f32_16x16x32_bf16(av, bv, acc, 0, 0, 0);
        }
    } else {
        #pragma unroll 4
        for (int it = 0; it < 32; it++) {
            int k = kh * 1024 + it * 32 + quad * 8;
            short8 av = *(const short8*)&hin[abase + k];
            float4 f0 = *(const float4*)&W32[wr + k];
            float4 f1 = *(const float4*)&W32[wr + k + 4];
            short8 bv = pack8(f0, f1);
            acc = __builtin_amdgcn_mfma_f32_16x16x32_bf16(av, bv, acc, 0, 0, 0);
        }
    }
    for (int e = 0; e < 4; e++)
        lds[w * 256 + (quad * 4 + e) * 16 + m16] = acc[e];
    __syncthreads();

    if (tid < 256) {
        int m = tid >> 4, u = tid & 15;
        int colu = bk * 16 + u;
        float gate[4];
        #pragma unroll
        for (int gg = 0; gg < 4; gg++) {
            float s = lds[gg * 256 + m * 16 + u] + lds[(gg + 4) * 256 + m * 16 + u];
            gate[gg] = s + Gt[(long)m * 8192 + gg * 2048 + colu];
        }
        float iv = sigf(gate[0]), fv = sigf(gate[1]);
        float gv = tanhf(gate[2]), ov = sigf(gate[3]);
        long ci = (long)m * 2048 + colu;
        float cn = fv * c[ci] + iv * gv;
        c[ci] = cn;
        hout[ci] = f2b(ov * tanhf(cn));
    }
}

// ---------------------------------------------------------------------------
// Causal softmax over scores rows. grid (T, B), 256 threads (s index).
// ---------------------------------------------------------------------------
__global__ void softmax_causal(const float* __restrict__ S, unsigned short* __restrict__ P) {
    int t = blockIdx.x, b = blockIdx.y, s = threadIdx.x;
    __shared__ float red[256];
    long base = (long)b * 65536 + (long)t * 256;
    float x = (s <= t) ? S[base + s] : -3.0e38f;
    red[s] = x; __syncthreads();
    for (int o = 128; o > 0; o >>= 1) { if (s < o) red[s] = fmaxf(red[s], red[s + o]); __syncthreads(); }
    float mx = red[0]; __syncthreads();
    float e = (s <= t) ? expf(x - mx) : 0.f;
    red[s] = e; __syncthreads();
    for (int o = 128; o > 0; o >>= 1) { if (s < o) red[s] += red[s + o]; __syncthreads(); }
    float inv = 1.f / red[0];
    P[base + s] = f2b(e * inv);
}

// hsT[b][h][s] = hs[(s*16+b)*2048 + h]; 64x64 tiles via LDS.
__global__ void transpose_hs(const unsigned short* __restrict__ hs, unsigned short* __restrict__ hsT) {
    __shared__ unsigned short t_lds[64 * 68];
    int htile = blockIdx.x, stile = blockIdx.y, b = blockIdx.z;
    int tid = threadIdx.x;
    int sl = tid >> 2, hl = (tid & 3) * 16;
    const unsigned short* src = hs + ((long)(stile * 64 + sl) * 16 + b) * 2048 + htile * 64 + hl;
    *(uint4*)&t_lds[sl * 68 + hl] = *(const uint4*)(src);
    *(uint4*)&t_lds[sl * 68 + hl + 8] = *(const uint4*)(src + 8);
    __syncthreads();
    int hr = tid >> 2, sl2 = (tid & 3) * 16;
    unsigned short* dst = hsT + (long)b * 524288 + (long)(htile * 64 + hr) * 256 + stile * 64 + sl2;
    #pragma unroll
    for (int j = 0; j < 16; j++) dst[j] = t_lds[(sl2 + j) * 68 + hr];
}

// cat[row] = [hs[row] | ctx[row]]
__global__ void cat_kernel(const unsigned short* __restrict__ hs, const unsigned short* __restrict__ ctx,
                           unsigned short* __restrict__ cat) {
    int row = blockIdx.x, tid = threadIdx.x;
    long r2 = (long)row * 2048, r4 = (long)row * 4096;
    *(uint4*)&cat[r4 + (long)tid * 8] = *(const uint4*)&hs[r2 + (long)tid * 8];
    *(uint4*)&cat[r4 + 2048 + (long)tid * 8] = *(const uint4*)&ctx[r2 + (long)tid * 8];
}

// ---------------------------------------------------------------------------
extern "C" void kernel_launch(void* const* d_in, const int* in_sizes, int n_in,
                              void* d_out, int out_size, void* d_ws, size_t ws_size,
                              hipStream_t stream) {
    (void)in_sizes; (void)n_in; (void)out_size; (void)ws_size;
    const int*  ids  = (const int*)d_in[0];
    const void* h0   = d_in[1];
    const void* c0   = d_in[2];
    const void* emb  = d_in[3];
    const void* Wih  = d_in[4];
    const void* Whh  = d_in[5];
    const void* bias = d_in[6];
    const void* Watt = d_in[7];
    const void* batt = d_in[8];
    const void* decW = d_in[9];
    const void* decb = d_in[10];

    char* ws = (char*)d_ws;
    size_t o = 0;
    auto alloc = [&](size_t bytes) { void* p = ws + o; o += (bytes + 255) & ~(size_t)255; return p; };
    int*            flag  = (int*)alloc(256);
    float*          G     = (float*)alloc((size_t)4096 * 8192 * 4);   // 134 MB
    unsigned short* Xa    = (unsigned short*)alloc((size_t)4096 * 2048 * 2);
    unsigned short* Xb    = (unsigned short*)alloc((size_t)4096 * 2048 * 2);
    unsigned short* h0buf = (unsigned short*)alloc(32768 * 2);
    float*          cbuf  = (float*)alloc(32768 * 4);
    // attention scratch aliases G (dead after the LSTM layers)
    char* gb = (char*)G;
    float*          scores = (float*)(gb);
    unsigned short* P      = (unsigned short*)(gb + 4194304);
    unsigned short* hsT    = (unsigned short*)(gb + 6291456);
    unsigned short* ctx    = (unsigned short*)(gb + 23068672);
    unsigned short* cat    = (unsigned short*)(gb + 39845888);
    unsigned short* outp   = (unsigned short*)(gb + 73400320);

    detect_dtype<<<1, 256, 0, stream>>>((const unsigned short*)emb, flag);
    embed_kernel<<<4096, 256, 0, stream>>>(ids, emb, flag, Xa);

    unsigned short* Xin = Xa;
    unsigned short* Xout = Xb;
    for (int l = 0; l < 3; l++) {
        init_state<<<128, 256, 0, stream>>>(h0, c0, (long)l * 32768, flag, h0buf, cbuf);
        // G = Xin @ Wih[l]^T + b[l]   (fp32 out)
        gemm_bt<<<dim3(64, 32, 1), 256, 0, stream>>>(
            Xin, Wih, (long)l * 8192 * 2048, 1,
            bias, (long)l * 8192, 1, 1,
            G, 0, flag,
            4096, 8192, 2048,
            2048, 2048, 8192,
            0, 0, 0, 1.f, 0);
        for (int t = 0; t < 256; t++) {
            lstm_step<<<128, 512, 0, stream>>>(
                G + (long)t * 16 * 8192, Whh, (long)l * 8192 * 2048, flag,
                (t == 0) ? h0buf : (Xout + (long)(t - 1) * 32768),
                Xout + (long)t * 32768, cbuf);
        }
        unsigned short* tmp = Xin; Xin = Xout; Xout = tmp;
    }
    unsigned short* hs = Xin;  // last layer hidden states [4096, 2048] bf16

    // scores[b,t,s] = hs_t . hs_s / sqrt(H)
    gemm_bt<<<dim3(2, 2, 16), 256, 0, stream>>>(
        hs, hs, 0, 0, nullptr, 0, 0, 0,
        scores, 0, flag,
        256, 256, 2048,
        32768, 32768, 256,
        2048, 2048, 65536, 0.022097086912079608f, 0);
    softmax_causal<<<dim3(256, 16), 256, 0, stream>>>(scores, P);
    transpose_hs<<<dim3(32, 4, 16), 256, 0, stream>>>(hs, hsT);
    // ctx = P @ hsT^T
    gemm_bt<<<dim3(16, 2, 16), 256, 0, stream>>>(
        P, hsT, 0, 0, nullptr, 0, 0, 0,
        ctx, 1, flag,
        256, 2048, 256,
        256, 256, 32768,
        65536, 524288, 2048, 1.f, 0);
    cat_kernel<<<4096, 256, 0, stream>>>(hs, ctx, cat);
    // out = tanh(cat @ W_att^T + b_att)
    gemm_bt<<<dim3(16, 32, 1), 256, 0, stream>>>(
        cat, Watt, 0, 1, batt, 0, 1, 1,
        outp, 1, flag,
        4096, 2048, 4096,
        4096, 4096, 2048,
        0, 0, 0, 1.f, 1);
    // decoded = out @ dec_W^T + dec_b  -> d_out (bf16, or f32 if flag)
    gemm_bt<<<dim3(250, 32, 1), 256, 0, stream>>>(
        outp, decW, 0, 1, decb, 0, 1, 1,
        d_out, 2, flag,
        4096, 32000, 2048,
        2048, 2048, 32000,
        0, 0, 0, 1.f, 0);
}